// Round 2
// baseline (74.344 us; speedup 1.0000x reference)
//
#include <hip/hip_runtime.h>

// N=4096 rows, F=256 features, H=4 heads.
// softmax_j(s_i[i,h] + s_j[j,h] + b[h]) == softmax_j(s_j[j,h])  (i,h-const terms
// cancel), so the output is ONE length-F vector broadcast to all N rows:
//   v[f] = (1/H) * sum_h ( sum_j exp(s_j[j,h]) * x[j,f] ) / ( sum_j exp(s_j[j,h]) )
//   out[i,f] = leaky_relu(v[f], 0.2).
//
// 2 dispatches, no memset, no atomics:
//   k1 (64 blocks × 64 rows): per-block partials (plain stores -> poison-safe)
//   k2 (64 blocks × 64 rows): 64-way partial reduce (redundant, ~263KB from L2
//       per block) + finalize + broadcast write.

#define NROWS 4096
#define FDIM  256
#define HHEADS 4
#define RPB 64          // rows per k1 block
#define NB1 (NROWS / RPB)   // 64
#define PAD 260         // 16B-aligned rows; (4r+c)%32 banks -> <=2-way (free)

// ws layout: partU[NB1][H][F] floats, then partZ[NB1][H] floats.

__global__ __launch_bounds__(256) void k1_partials(const float* __restrict__ x,
                                                   const float* __restrict__ W,
                                                   float* __restrict__ partU,
                                                   float* __restrict__ partZ) {
    __shared__ float x_lds[RPB * PAD];
    __shared__ float w_lds[HHEADS * FDIM];   // w_lds[h*256+c] = W2[h][c]
    __shared__ float e_lds[RPB * HHEADS];

    const int t = threadIdx.x;
    const int row0 = blockIdx.x * RPB;

    // Stage W2 (= W[:, F:2F], row stride 512) into LDS, per-head contiguous.
    for (int i = t; i < HHEADS * FDIM; i += 256) {
        int h = i >> 8, c = i & 255;
        w_lds[i] = W[h * (2 * FDIM) + FDIM + c];
    }
    // Stage 64 x-rows with coalesced float4 loads.
    for (int i = t; i < RPB * (FDIM / 4); i += 256) {
        int r = i >> 6, c4 = i & 63;
        float4 v = ((const float4*)x)[(size_t)(row0 + r) * (FDIM / 4) + c4];
        *(float4*)&x_lds[r * PAD + c4 * 4] = v;
    }
    __syncthreads();

    // Phase 1: one (row, head) pair per thread; float4 LDS dot product.
    {
        int r = t >> 2, h = t & 3;
        const float4* xr = (const float4*)&x_lds[r * PAD];     // 1040B-aligned rows
        const float4* wr = (const float4*)&w_lds[h * FDIM];
        float acc = 0.f;
        #pragma unroll 8
        for (int c = 0; c < FDIM / 4; ++c) {
            float4 a = xr[c], b = wr[c];
            acc = fmaf(a.x, b.x, fmaf(a.y, b.y, fmaf(a.z, b.z, fmaf(a.w, b.w, acc))));
        }
        e_lds[r * 4 + h] = __expf(acc);   // |s| < ~3: no max-shift needed in fp32
    }
    __syncthreads();

    // Per-block softmax-denominator partials (plain store).
    if (t < HHEADS) {
        float z = 0.f;
        for (int r = 0; r < RPB; ++r) z += e_lds[r * 4 + t];
        partZ[blockIdx.x * HHEADS + t] = z;
    }

    // Phase 2: partial u[h][f] = sum_r e[r,h]*x[r,f];  f = t. Plain stores.
    float a0 = 0.f, a1 = 0.f, a2 = 0.f, a3 = 0.f;
    for (int r = 0; r < RPB; ++r) {
        float xv = x_lds[r * PAD + t];
        float4 e4 = *(const float4*)&e_lds[r * 4];
        a0 = fmaf(e4.x, xv, a0);
        a1 = fmaf(e4.y, xv, a1);
        a2 = fmaf(e4.z, xv, a2);
        a3 = fmaf(e4.w, xv, a3);
    }
    float* pu = partU + (size_t)blockIdx.x * (HHEADS * FDIM);
    pu[0 * FDIM + t] = a0;
    pu[1 * FDIM + t] = a1;
    pu[2 * FDIM + t] = a2;
    pu[3 * FDIM + t] = a3;
}

// k2: redundant 64-way reduce per block, finalize v, broadcast-write 64 rows.
__global__ __launch_bounds__(256) void k2_out(const float* __restrict__ partU,
                                              const float* __restrict__ partZ,
                                              float* __restrict__ out) {
    __shared__ float v_lds[FDIM];
    __shared__ float zinv[HHEADS];
    const int t = threadIdx.x;

    if (t < HHEADS) {
        float z = 0.f;
        for (int b = 0; b < NB1; ++b) z += partZ[b * HHEADS + t];
        zinv[t] = 1.0f / z;
    }

    float u0 = 0.f, u1 = 0.f, u2 = 0.f, u3 = 0.f;
    for (int b = 0; b < NB1; ++b) {
        const float* p = partU + (size_t)b * (HHEADS * FDIM);
        u0 += p[0 * FDIM + t];
        u1 += p[1 * FDIM + t];
        u2 += p[2 * FDIM + t];
        u3 += p[3 * FDIM + t];
    }
    __syncthreads();   // zinv visible

    float val = 0.25f * (u0 * zinv[0] + u1 * zinv[1] + u2 * zinv[2] + u3 * zinv[3]);
    v_lds[t] = val > 0.f ? val : 0.2f * val;
    __syncthreads();

    const int row0 = blockIdx.x * 64;
    float4* out4 = (float4*)out;
    #pragma unroll
    for (int i = 0; i < 16; ++i) {
        int idx = t + i * 256;            // 0..4095 -> 64 rows × 64 float4
        int r = idx >> 6, c4 = idx & 63;
        out4[(size_t)(row0 + r) * (FDIM / 4) + c4] = *(const float4*)&v_lds[c4 * 4];
    }
}

extern "C" void kernel_launch(void* const* d_in, const int* in_sizes, int n_in,
                              void* d_out, int out_size, void* d_ws, size_t ws_size,
                              hipStream_t stream) {
    const float* x = (const float*)d_in[0];   // (4096, 256)
    const float* W = (const float*)d_in[1];   // (4, 512)
    // d_in[2] = b is unused: it cancels in the softmax.
    float* partU = (float*)d_ws;                          // NB1*H*F floats
    float* partZ = partU + (size_t)NB1 * HHEADS * FDIM;   // NB1*H floats
    float* out = (float*)d_out;

    k1_partials<<<NB1, 256, 0, stream>>>(x, W, partU, partZ);
    k2_out<<<NROWS / 64, 256, 0, stream>>>(partU, partZ, out);
}

// Round 3
// 72.702 us; speedup vs baseline: 1.0226x; 1.0226x over previous
//
#include <hip/hip_runtime.h>

// N=4096 rows, F=256 features, H=4 heads.
// softmax_j(s_i[i,h] + s_j[j,h] + b[h]) == softmax_j(s_j[j,h])  (i,h-const terms
// cancel), so the output is ONE length-F vector broadcast to all N rows:
//   v[f] = (1/H) * sum_h ( sum_j exp(s_j[j,h]) * x[j,f] ) / ( sum_j exp(s_j[j,h]) )
//   out[i,f] = leaky_relu(v[f], 0.2).
//
// 3 dispatches, no memset, no atomics, no redundant bulk reads:
//   k1    (128 blocks × 32 rows): per-block partials, plain stores (poison-safe)
//   kred  (16 blocks × 16 cols):  partials -> final v[256] (reads ~0.5MB once)
//   kbcast(256 blocks × 16 rows): broadcast v, pure 4MB coalesced write

#define NROWS 4096
#define FDIM  256
#define HH    4
#define RPB   32
#define NB1   128            // k1 blocks / partial count
#define PAD   260            // 16B-aligned rows; (4r+c)%32 banks -> <=2-way (free)

// ws layout: partU[NB1][HH][FDIM], partZ[NB1][HH], v[FDIM]

__global__ __launch_bounds__(256) void k1_partials(const float* __restrict__ x,
                                                   const float* __restrict__ W,
                                                   float* __restrict__ partU,
                                                   float* __restrict__ partZ) {
    __shared__ float x_lds[RPB * PAD];
    __shared__ float w_lds[HH * FDIM];   // w_lds[h*256+c] = W2[h][c]
    __shared__ float e_lds[RPB * HH];

    const int t = threadIdx.x;
    const int row0 = blockIdx.x * RPB;

    // Stage W2 (= W[:, F:2F], row stride 512) into LDS, per-head contiguous.
    for (int i = t; i < HH * FDIM; i += 256) {
        int h = i >> 8, c = i & 255;
        w_lds[i] = W[h * (2 * FDIM) + FDIM + c];
    }
    // Stage 32 x-rows with coalesced float4 loads (8 per thread, independent).
    for (int i = t; i < RPB * (FDIM / 4); i += 256) {
        int r = i >> 6, c4 = i & 63;
        float4 v = ((const float4*)x)[(size_t)(row0 + r) * (FDIM / 4) + c4];
        *(float4*)&x_lds[r * PAD + c4 * 4] = v;
    }
    __syncthreads();

    // Phase 1: 128 (row,head) pairs, 2 threads per pair (half-dot + shfl reduce).
    {
        int pair = t >> 1, half = t & 1;
        int r = pair >> 2, h = pair & 3;
        const float4* xr = (const float4*)&x_lds[r * PAD];
        const float4* wr = (const float4*)&w_lds[h * FDIM];
        float acc = 0.f;
        #pragma unroll
        for (int c = half * 32; c < half * 32 + 32; ++c) {
            float4 a = xr[c], b = wr[c];
            acc = fmaf(a.x, b.x, fmaf(a.y, b.y, fmaf(a.z, b.z, fmaf(a.w, b.w, acc))));
        }
        acc += __shfl_xor(acc, 1);
        if (half == 0) e_lds[r * 4 + h] = __expf(acc);  // |s|<~3: no max-shift needed
    }
    __syncthreads();

    // Softmax-denominator partials (plain store).
    if (t < HH) {
        float z = 0.f;
        for (int r = 0; r < RPB; ++r) z += e_lds[r * 4 + t];
        partZ[blockIdx.x * HH + t] = z;
    }

    // Phase 2: partial u[h][f] = sum_r e[r,h]*x[r,f];  f = t. Plain stores.
    float a0 = 0.f, a1 = 0.f, a2 = 0.f, a3 = 0.f;
    for (int r = 0; r < RPB; ++r) {
        float xv = x_lds[r * PAD + t];
        float4 e4 = *(const float4*)&e_lds[r * 4];
        a0 = fmaf(e4.x, xv, a0);
        a1 = fmaf(e4.y, xv, a1);
        a2 = fmaf(e4.z, xv, a2);
        a3 = fmaf(e4.w, xv, a3);
    }
    float* pu = partU + (size_t)blockIdx.x * (HH * FDIM);
    pu[0 * FDIM + t] = a0;
    pu[1 * FDIM + t] = a1;
    pu[2 * FDIM + t] = a2;
    pu[3 * FDIM + t] = a3;
}

// kred: 16 blocks, block g reduces columns [g*16, g*16+16) across all partials
// and heads, applies 1/Z and leaky_relu, writes v[256]. Total read ~0.5MB once.
__global__ __launch_bounds__(256) void kred(const float* __restrict__ partU,
                                            const float* __restrict__ partZ,
                                            float* __restrict__ v) {
    __shared__ float red[4][HH][16];   // [bq][h][cl]
    __shared__ float zinv[HH];
    const int t = threadIdx.x;
    const int cl = t & 15, h = (t >> 4) & 3, bq = t >> 6;
    const int g = blockIdx.x;

    float s = 0.f;
    const int b0 = bq * (NB1 / 4);
    #pragma unroll 8
    for (int b = b0; b < b0 + NB1 / 4; ++b)
        s += partU[(size_t)b * (HH * FDIM) + h * FDIM + g * 16 + cl];
    red[bq][h][cl] = s;

    if (t < HH) {
        float z = 0.f;
        #pragma unroll 8
        for (int b = 0; b < NB1; ++b) z += partZ[b * HH + t];
        zinv[t] = 0.25f / z;
    }
    __syncthreads();

    if (t < 16) {
        float val = 0.f;
        #pragma unroll
        for (int h2 = 0; h2 < HH; ++h2) {
            float uh = red[0][h2][t] + red[1][h2][t] + red[2][h2][t] + red[3][h2][t];
            val = fmaf(uh, zinv[h2], val);
        }
        val = val > 0.f ? val : 0.2f * val;
        v[g * 16 + t] = val;
    }
}

// kbcast: 256 blocks × 16 rows, pure coalesced float4 broadcast write.
__global__ __launch_bounds__(256) void kbcast(const float* __restrict__ v,
                                              float* __restrict__ out) {
    __shared__ float v_lds[FDIM];
    const int t = threadIdx.x;
    v_lds[t] = v[t];
    __syncthreads();

    const int row0 = blockIdx.x * 16;
    const int c4 = t & 63;
    float4 val4 = *(const float4*)&v_lds[c4 * 4];
    float4* out4 = (float4*)out;
    #pragma unroll
    for (int i = 0; i < 4; ++i) {
        int r = (t >> 6) + i * 4;    // rows 0..15
        out4[(size_t)(row0 + r) * (FDIM / 4) + c4] = val4;
    }
}

extern "C" void kernel_launch(void* const* d_in, const int* in_sizes, int n_in,
                              void* d_out, int out_size, void* d_ws, size_t ws_size,
                              hipStream_t stream) {
    const float* x = (const float*)d_in[0];   // (4096, 256)
    const float* W = (const float*)d_in[1];   // (4, 512)
    // d_in[2] = b is unused: it cancels in the softmax.
    float* partU = (float*)d_ws;                          // NB1*HH*FDIM floats
    float* partZ = partU + (size_t)NB1 * HH * FDIM;       // NB1*HH floats
    float* v     = partZ + NB1 * HH;                      // FDIM floats
    float* out = (float*)d_out;

    k1_partials<<<NB1, 256, 0, stream>>>(x, W, partU, partZ);
    kred<<<16, 256, 0, stream>>>(partU, partZ, v);
    kbcast<<<NROWS / 16, 256, 0, stream>>>(v, out);
}